// Round 1
// baseline (126.776 us; speedup 1.0000x reference)
//
#include <hip/hip_runtime.h>

#define NB 64
#define NT 1024
#define NA 512
#define NF 32
#define KW 31
#define PADW 15
#define TB 32

__device__ __forceinline__ float fast_tanh(float x) {
    // tanh(x) = 1 - 2/(1+exp(2x));  exp(2x) = exp2(x * 2/ln2)
    float e = __builtin_amdgcn_exp2f(x * 2.885390081777927f);
    return 1.0f - 2.0f * __builtin_amdgcn_rcpf(1.0f + e);
}

__device__ __forceinline__ float fast_sigmoid(float u) {
    return __builtin_amdgcn_rcpf(1.0f + __builtin_amdgcn_exp2f(-u * 1.4426950408889634f));
}

// ---------------- kernel A: pq[b][a] = sum_k query[b][k] * W_w[a][k] + W_b[a]
__global__ __launch_bounds__(256) void lsa_pq(
    const float* __restrict__ query, const float* __restrict__ Ww,
    const float* __restrict__ Wb, float* __restrict__ pq)
{
    __shared__ float qs[NA];
    int tid = threadIdx.x;
    int b = blockIdx.x >> 1;
    int a0 = (blockIdx.x & 1) * 256;
    qs[tid]       = query[b * NA + tid];
    qs[tid + 256] = query[b * NA + tid + 256];
    __syncthreads();
    int a = a0 + tid;
    const float4* wr = (const float4*)(Ww + (long)a * NA);
    float acc  = Wb[a];
    float acc2 = 0.f;
#pragma unroll 8
    for (int k = 0; k < NA / 4; ++k) {
        float4 w = wr[k];
        float4 q4 = *(const float4*)(qs + 4 * k);   // lane-uniform -> LDS broadcast
        acc  += w.x * q4.x + w.y * q4.y;
        acc2 += w.z * q4.z + w.w * q4.w;
    }
    pq[b * NA + a] = acc + acc2;
}

// ---------------- kernel B (hot): u -> s = sigmoid(u), written to d_out
// block = 256 threads, handles (b, chunk of TB t's). thread owns a = 2*tid, 2*tid+1.
__global__ __launch_bounds__(256) void lsa_main(
    const float* __restrict__ enc, const float* __restrict__ cum,
    const float* __restrict__ att, const float* __restrict__ convw,
    const float* __restrict__ Lw, const float* __restrict__ Lb,
    const float* __restrict__ vw, const float* __restrict__ pq,
    float* __restrict__ sout)
{
    __shared__ float cum_s[TB + 30];
    __shared__ float att_s[TB + 30];
    __shared__ float cw_s[2][KW][NF];      // transposed: [c][k][f] -> bank = f, conflict-free
    __shared__ float4 cvs[TB][NF / 4];     // conv output per t, broadcast-read
    __shared__ float wred[4][TB];

    int tid = threadIdx.x;
    int b  = blockIdx.x >> 5;              // NT/TB = 32 chunks
    int t0 = (blockIdx.x & 31) * TB;

    // stage cum/att slice with zero padding
    if (tid < TB + 30) {
        int t = t0 - PADW + tid;
        bool ok = (t >= 0) && (t < NT);
        cum_s[tid] = ok ? cum[b * NT + t] : 0.f;
        att_s[tid] = ok ? att[b * NT + t] : 0.f;
    }
    // stage conv_w transposed [c][k][f]
    for (int i = tid; i < NF * 2 * KW; i += 256) {
        int f = i / (2 * KW);
        int r = i - f * 2 * KW;
        int c = r / KW;
        int k = r - c * KW;
        cw_s[c][k][f] = convw[i];
    }

    // per-thread constants: 2 rows of L_w in registers (64 floats)
    int a0 = 2 * tid;
    float4 lw0[8], lw1[8];
    {
        const float4* p = (const float4*)(Lw + (long)a0 * NF);
#pragma unroll
        for (int i = 0; i < 8; ++i) lw0[i] = p[i];
#pragma unroll
        for (int i = 0; i < 8; ++i) lw1[i] = p[8 + i];
    }
    float2 pqv = *(const float2*)(pq + b * NA + a0);
    float2 lbv = *(const float2*)(Lb + a0);
    float2 vv  = *(const float2*)(vw + a0);
    float c0 = pqv.x + lbv.x;
    float c1 = pqv.y + lbv.y;
    __syncthreads();

    // conv: cvs[tt][f] = sum_k cum_s[tt+k]*cw[0][k][f] + att_s[tt+k]*cw[1][k][f]
    {
        int f   = tid & 31;
        int ttb = tid >> 5;                 // 0..7
#pragma unroll
        for (int p = 0; p < 4; ++p) {
            int tt = p * 8 + ttb;
            float acc = 0.f;
#pragma unroll
            for (int k = 0; k < KW; ++k) {
                acc += cum_s[tt + k] * cw_s[0][k][f] + att_s[tt + k] * cw_s[1][k][f];
            }
            ((float*)&cvs[tt][0])[f] = acc;
        }
    }
    __syncthreads();

    int wid  = tid >> 6;
    int lane = tid & 63;
    const float* erow = enc + ((long)b * NT + t0) * NA + a0;

#pragma unroll 4
    for (int tt = 0; tt < TB; ++tt) {
        float2 e = *(const float2*)(erow + (long)tt * NA);
        float x0 = c0 + e.x;
        float x1 = c1 + e.y;
#pragma unroll
        for (int q = 0; q < 8; ++q) {
            float4 cf = cvs[tt][q];          // lane-uniform -> broadcast
            x0 += cf.x * lw0[q].x + cf.y * lw0[q].y + cf.z * lw0[q].z + cf.w * lw0[q].w;
            x1 += cf.x * lw1[q].x + cf.y * lw1[q].y + cf.z * lw1[q].z + cf.w * lw1[q].w;
        }
        float part = fast_tanh(x0) * vv.x + fast_tanh(x1) * vv.y;
#pragma unroll
        for (int m = 32; m >= 1; m >>= 1)
            part += __shfl_xor(part, m, 64);
        if (lane == 0) wred[wid][tt] = part;
    }
    __syncthreads();
    if (tid < TB) {
        float u = wred[0][tid] + wred[1][tid] + wred[2][tid] + wred[3][tid];
        sout[b * NT + t0 + tid] = fast_sigmoid(u);
    }
}

// ---------------- kernel C: in-place normalize with alpha recursion + mask
__global__ __launch_bounds__(256) void lsa_norm(
    const float* __restrict__ alpha, const int* __restrict__ plen,
    float* __restrict__ out)
{
    __shared__ float red[4];
    int tid = threadIdx.x;
    int b = blockIdx.x;
    int pl = plen[b];
    float w[4];
    float psum = 0.f;
#pragma unroll
    for (int j = 0; j < 4; ++j) {
        int t = tid + 256 * j;
        float s   = out[b * NT + t];
        float al  = alpha[b * NT + t];
        float am1 = (t >= 1) ? alpha[b * NT + t - 1] : 0.f;
        float am2 = (t >= 2) ? alpha[b * NT + t - 2] : 0.f;
        float val = (t < pl) ? (al + am1 + am2 + 1e-7f) * s : 0.f;
        w[j] = val;
        psum += val;
    }
#pragma unroll
    for (int m = 32; m >= 1; m >>= 1) psum += __shfl_xor(psum, m, 64);
    int lane = tid & 63, wid = tid >> 6;
    if (lane == 0) red[wid] = psum;
    __syncthreads();
    float total = red[0] + red[1] + red[2] + red[3];
    float inv = 1.0f / total;
#pragma unroll
    for (int j = 0; j < 4; ++j) {
        int t = tid + 256 * j;
        out[b * NT + t] = w[j] * inv;
    }
}

extern "C" void kernel_launch(void* const* d_in, const int* in_sizes, int n_in,
                              void* d_out, int out_size, void* d_ws, size_t ws_size,
                              hipStream_t stream)
{
    const float* enc   = (const float*)d_in[0];
    const float* query = (const float*)d_in[1];
    const float* cum   = (const float*)d_in[2];
    const float* att   = (const float*)d_in[3];
    const float* alpha = (const float*)d_in[4];
    const float* convw = (const float*)d_in[5];
    const float* Lw    = (const float*)d_in[6];
    const float* Lb    = (const float*)d_in[7];
    const float* Ww    = (const float*)d_in[8];
    const float* Wb    = (const float*)d_in[9];
    const float* vw    = (const float*)d_in[10];
    const int*   plen  = (const int*)d_in[12];

    float* pq   = (float*)d_ws;            // NB*NA floats = 128 KB
    float* sout = (float*)d_out;           // s then normalized alpha, in place

    lsa_pq  <<<NB * 2,        256, 0, stream>>>(query, Ww, Wb, pq);
    lsa_main<<<NB * (NT / TB), 256, 0, stream>>>(enc, cum, att, convw, Lw, Lb, vw, pq, sout);
    lsa_norm<<<NB,            256, 0, stream>>>(alpha, plen, sout);
}

// Round 3
// 73.806 us; speedup vs baseline: 1.7177x; 1.7177x over previous
//
#include <hip/hip_runtime.h>

#define NB 64
#define NT 1024
#define NA 512
#define NF 32
#define KW 31
#define PADW 15
#define TB 32

typedef __fp16 half2v __attribute__((ext_vector_type(2)));

__device__ __forceinline__ float fast_tanh(float x) {
    float e = __builtin_amdgcn_exp2f(x * 2.885390081777927f);
    return 1.0f - 2.0f * __builtin_amdgcn_rcpf(1.0f + e);
}
__device__ __forceinline__ float fast_sigmoid(float u) {
    return __builtin_amdgcn_rcpf(1.0f + __builtin_amdgcn_exp2f(-u * 1.4426950408889634f));
}
__device__ __forceinline__ unsigned pkrtz(float a, float b) {
    half2v h = __builtin_amdgcn_cvt_pkrtz(a, b);
    return __builtin_bit_cast(unsigned, h);
}
__device__ __forceinline__ float fdot2u(unsigned cv, unsigned lw, float acc) {
#if __has_builtin(__builtin_amdgcn_fdot2)
    return __builtin_amdgcn_fdot2(__builtin_bit_cast(half2v, cv),
                                  __builtin_bit_cast(half2v, lw), acc, false);
#else
    half2v a = __builtin_bit_cast(half2v, cv), b = __builtin_bit_cast(half2v, lw);
    return acc + (float)a.x * (float)b.x + (float)a.y * (float)b.y;
#endif
}

// ---------------- kernel A: pq = query @ W_w^T + W_b ; block 0 also transposes conv_w
__global__ __launch_bounds__(256) void lsa_pq(
    const float* __restrict__ query, const float* __restrict__ Ww,
    const float* __restrict__ Wb, const float* __restrict__ convw,
    float* __restrict__ pq, float* __restrict__ cwT)
{
    if (blockIdx.x == 0) {
        for (int i = threadIdx.x; i < NF * 2 * KW; i += 256) {
            int f = i / (2 * KW);
            int r = i - f * 2 * KW;
            int c = r / KW;
            int k = r - c * KW;
            cwT[(c * KW + k) * NF + f] = convw[i];   // [c][k][f]
        }
    }
    __shared__ float qs[NA];
    int tid = threadIdx.x;
    int b = blockIdx.x >> 1;
    int a0 = (blockIdx.x & 1) * 256;
    qs[tid]       = query[b * NA + tid];
    qs[tid + 256] = query[b * NA + tid + 256];
    __syncthreads();
    int a = a0 + tid;
    const float4* wr = (const float4*)(Ww + (long)a * NA);
    float acc  = Wb[a];
    float acc2 = 0.f;
#pragma unroll 8
    for (int k = 0; k < NA / 4; ++k) {
        float4 w = wr[k];
        float4 q4 = *(const float4*)(qs + 4 * k);
        acc  += w.x * q4.x + w.y * q4.y;
        acc2 += w.z * q4.z + w.w * q4.w;
    }
    pq[b * NA + a] = acc + acc2;
}

// ---------------- kernel B (hot): s = sigmoid(u) -> d_out
__global__ __launch_bounds__(256, 3) void lsa_main(
    const float* __restrict__ enc, const float* __restrict__ cum,
    const float* __restrict__ att, const float* __restrict__ cwT,
    const float* __restrict__ Lw, const float* __restrict__ Lb,
    const float* __restrict__ vw, const float* __restrict__ pq,
    float* __restrict__ sout)
{
    __shared__ float cum_s[TB + 30];
    __shared__ float att_s[TB + 30];
    __shared__ unsigned cvsh[TB][20];     // f16x2 conv output: 16 pairs used, pad to 20
    __shared__ float red[256][36];        // partial[thread][tt], stride 36 (16B-aligned rows)
    __shared__ float red2[8][36];

    int tid = threadIdx.x;
    int b  = blockIdx.x >> 5;
    int t0 = (blockIdx.x & 31) * TB;

    // ---- per-thread constants (issue global loads early)
    int a0 = 2 * tid;
    const float4* lp = (const float4*)(Lw + (long)a0 * NF);
    float4 lf[16];
#pragma unroll
    for (int i = 0; i < 16; ++i) lf[i] = lp[i];
    float c0 = pq[b * NA + a0]     + Lb[a0];
    float c1 = pq[b * NA + a0 + 1] + Lb[a0 + 1];
    float vx = vw[a0], vy = vw[a0 + 1];

    // ---- stage cum/att slice
    if (tid < TB + 30) {
        int t = t0 - PADW + tid;
        bool ok = (t >= 0) && (t < NT);
        cum_s[tid] = ok ? cum[b * NT + t] : 0.f;
        att_s[tid] = ok ? att[b * NT + t] : 0.f;
    }

    // ---- L_w rows -> half2 registers (32 VGPRs)
    unsigned h0[16], h1[16];
#pragma unroll
    for (int i = 0; i < 8; ++i) {
        h0[2 * i]     = pkrtz(lf[i].x, lf[i].y);
        h0[2 * i + 1] = pkrtz(lf[i].z, lf[i].w);
        h1[2 * i]     = pkrtz(lf[8 + i].x, lf[8 + i].y);
        h1[2 * i + 1] = pkrtz(lf[8 + i].z, lf[8 + i].w);
    }
    __syncthreads();

    // ---- conv phase: wave w computes filters [8w, 8w+8) for all 32 tt.
    // weights are wave-uniform -> scalar loads; lanes 32-63 duplicate (cheap).
    {
        int lane = tid & 63;
        int tt = lane & 31;
        int fbu = __builtin_amdgcn_readfirstlane(tid >> 6) * 8;
        const float* cw = cwT + fbu;
        float acc[8] = {0, 0, 0, 0, 0, 0, 0, 0};
        for (int k = 0; k < KW; ++k) {
            float x0 = cum_s[tt + k];
            float x1 = att_s[tt + k];
#pragma unroll
            for (int f8 = 0; f8 < 8; ++f8) {
                acc[f8] = fmaf(x0, cw[k * NF + f8],
                          fmaf(x1, cw[(KW + k) * NF + f8], acc[f8]));
            }
        }
        if (lane < 32) {
            uint4 pk;
            pk.x = pkrtz(acc[0], acc[1]);
            pk.y = pkrtz(acc[2], acc[3]);
            pk.z = pkrtz(acc[4], acc[5]);
            pk.w = pkrtz(acc[6], acc[7]);
            *(uint4*)&cvsh[tt][fbu >> 1] = pk;   // 16B-aligned: (20*tt + fbu/2)*4
        }
    }
    __syncthreads();

    // ---- main loop: 32 tt, per-thread 2 a's, f16 dot2 against broadcast conv
    float p32[TB];
    const float* erow = enc + ((long)b * NT + t0) * NA + a0;
#pragma unroll
    for (int tt = 0; tt < TB; ++tt) {
        float2 e = *(const float2*)(erow + (long)tt * NA);
        float x0[2] = {c0 + e.x, 0.f};
        float x1[2] = {c1 + e.y, 0.f};
#pragma unroll
        for (int q = 0; q < 4; ++q) {
            uint4 cv = *(const uint4*)&cvsh[tt][4 * q];
            int p = q & 1;
            x0[p] = fdot2u(cv.x, h0[4 * q + 0], x0[p]);
            x0[p] = fdot2u(cv.y, h0[4 * q + 1], x0[p]);
            x0[p] = fdot2u(cv.z, h0[4 * q + 2], x0[p]);
            x0[p] = fdot2u(cv.w, h0[4 * q + 3], x0[p]);
            x1[p] = fdot2u(cv.x, h1[4 * q + 0], x1[p]);
            x1[p] = fdot2u(cv.y, h1[4 * q + 1], x1[p]);
            x1[p] = fdot2u(cv.z, h1[4 * q + 2], x1[p]);
            x1[p] = fdot2u(cv.w, h1[4 * q + 3], x1[p]);
        }
        p32[tt] = fast_tanh(x0[0] + x0[1]) * vx + fast_tanh(x1[0] + x1[1]) * vy;
    }

    // ---- reduction: regs -> LDS transpose (no shuffles)
#pragma unroll
    for (int q = 0; q < 8; ++q) {
        float4 w4 = make_float4(p32[4 * q], p32[4 * q + 1], p32[4 * q + 2], p32[4 * q + 3]);
        *(float4*)&red[tid][4 * q] = w4;
    }
    __syncthreads();
    {
        int tt = tid & 31, seg = tid >> 5;
        float s = 0.f;
#pragma unroll
        for (int i = 0; i < 32; ++i) s += red[seg * 32 + i][tt];
        red2[seg][tt] = s;
    }
    __syncthreads();
    if (tid < 32) {
        float u = 0.f;
#pragma unroll
        for (int s = 0; s < 8; ++s) u += red2[s][tid];
        sout[b * NT + t0 + tid] = fast_sigmoid(u);
    }
}

// ---------------- kernel C: normalize with alpha recursion + mask (in place)
__global__ __launch_bounds__(256) void lsa_norm(
    const float* __restrict__ alpha, const int* __restrict__ plen,
    float* __restrict__ out)
{
    __shared__ float red[4];
    int tid = threadIdx.x;
    int b = blockIdx.x;
    int pl = plen[b];
    float w[4];
    float psum = 0.f;
#pragma unroll
    for (int j = 0; j < 4; ++j) {
        int t = tid + 256 * j;
        float s   = out[b * NT + t];
        float al  = alpha[b * NT + t];
        float am1 = (t >= 1) ? alpha[b * NT + t - 1] : 0.f;
        float am2 = (t >= 2) ? alpha[b * NT + t - 2] : 0.f;
        float val = (t < pl) ? (al + am1 + am2 + 1e-7f) * s : 0.f;
        w[j] = val;
        psum += val;
    }
#pragma unroll
    for (int m = 32; m >= 1; m >>= 1) psum += __shfl_xor(psum, m, 64);
    int lane = tid & 63, wid = tid >> 6;
    if (lane == 0) red[wid] = psum;
    __syncthreads();
    float total = red[0] + red[1] + red[2] + red[3];
    float inv = 1.0f / total;
#pragma unroll
    for (int j = 0; j < 4; ++j) {
        int t = tid + 256 * j;
        out[b * NT + t] = w[j] * inv;
    }
}

extern "C" void kernel_launch(void* const* d_in, const int* in_sizes, int n_in,
                              void* d_out, int out_size, void* d_ws, size_t ws_size,
                              hipStream_t stream)
{
    const float* enc   = (const float*)d_in[0];
    const float* query = (const float*)d_in[1];
    const float* cum   = (const float*)d_in[2];
    const float* att   = (const float*)d_in[3];
    const float* alpha = (const float*)d_in[4];
    const float* convw = (const float*)d_in[5];
    const float* Lw    = (const float*)d_in[6];
    const float* Lb    = (const float*)d_in[7];
    const float* Ww    = (const float*)d_in[8];
    const float* Wb    = (const float*)d_in[9];
    const float* vw    = (const float*)d_in[10];
    const int*   plen  = (const int*)d_in[12];

    float* pq  = (float*)d_ws;                       // 64*512 floats = 128 KB
    float* cwT = (float*)d_ws + NB * NA;             // 1984 floats
    float* sout = (float*)d_out;

    lsa_pq  <<<NB * 2,         256, 0, stream>>>(query, Ww, Wb, convw, pq, cwT);
    lsa_main<<<NB * (NT / TB), 256, 0, stream>>>(enc, cum, att, cwT, Lw, Lb, vw, pq, sout);
    lsa_norm<<<NB,             256, 0, stream>>>(alpha, plen, sout);
}

// Round 6
// 70.233 us; speedup vs baseline: 1.8051x; 1.0509x over previous
//
#include <hip/hip_runtime.h>

#define NB 64
#define NT 1024
#define NA 512
#define NF 32
#define KW 31
#define PADW 15
#define TB 32

typedef __fp16 half2v __attribute__((ext_vector_type(2)));

__device__ __forceinline__ float fast_tanh(float x) {
    float e = __builtin_amdgcn_exp2f(x * 2.885390081777927f);
    return 1.0f - 2.0f * __builtin_amdgcn_rcpf(1.0f + e);
}
__device__ __forceinline__ float fast_sigmoid(float u) {
    return __builtin_amdgcn_rcpf(1.0f + __builtin_amdgcn_exp2f(-u * 1.4426950408889634f));
}
__device__ __forceinline__ unsigned pkrtz(float a, float b) {
    half2v h = __builtin_amdgcn_cvt_pkrtz(a, b);
    return __builtin_bit_cast(unsigned, h);
}
__device__ __forceinline__ float fdot2u(unsigned cv, unsigned lw, float acc) {
#if __has_builtin(__builtin_amdgcn_fdot2)
    return __builtin_amdgcn_fdot2(__builtin_bit_cast(half2v, cv),
                                  __builtin_bit_cast(half2v, lw), acc, false);
#else
    half2v a = __builtin_bit_cast(half2v, cv), b = __builtin_bit_cast(half2v, lw);
    return acc + (float)a.x * (float)b.x + (float)a.y * (float)b.y;
#endif
}

// ---------------- kernel A: pq = query @ W_w^T + W_b ; block 0 also transposes conv_w
__global__ __launch_bounds__(256) void lsa_pq(
    const float* __restrict__ query, const float* __restrict__ Ww,
    const float* __restrict__ Wb, const float* __restrict__ convw,
    float* __restrict__ pq, float* __restrict__ cwT)
{
    if (blockIdx.x == 0) {
        for (int i = threadIdx.x; i < NF * 2 * KW; i += 256) {
            int f = i / (2 * KW);
            int r = i - f * 2 * KW;
            int c = r / KW;
            int k = r - c * KW;
            cwT[(c * KW + k) * NF + f] = convw[i];   // [c][k][f]
        }
    }
    __shared__ float qs[NA];
    int tid = threadIdx.x;
    int b = blockIdx.x >> 1;
    int a0 = (blockIdx.x & 1) * 256;
    qs[tid]       = query[b * NA + tid];
    qs[tid + 256] = query[b * NA + tid + 256];
    __syncthreads();
    int a = a0 + tid;
    const float4* wr = (const float4*)(Ww + (long)a * NA);
    float acc  = Wb[a];
    float acc2 = 0.f;
#pragma unroll 8
    for (int k = 0; k < NA / 4; ++k) {
        float4 w = wr[k];
        float4 q4 = *(const float4*)(qs + 4 * k);
        acc  += w.x * q4.x + w.y * q4.y;
        acc2 += w.z * q4.z + w.w * q4.w;
    }
    pq[b * NA + a] = acc + acc2;
}

// ---------------- kernel B (hot): s = sigmoid(u) -> d_out
__global__ __launch_bounds__(256, 4) void lsa_main(
    const float* __restrict__ enc, const float* __restrict__ cum,
    const float* __restrict__ att, const float* __restrict__ cwT,
    const float* __restrict__ Lw, const float* __restrict__ Lb,
    const float* __restrict__ vw, const float* __restrict__ pq,
    float* __restrict__ sout)
{
    __shared__ float cum_s[TB + 30];
    __shared__ float att_s[TB + 30];
    __shared__ unsigned cvsh[TB][20];     // f16x2 conv output: 16 pairs used, pad to 20
    __shared__ float wred[4][33];         // per-wave tt sums

    int tid = threadIdx.x;
    int b  = blockIdx.x >> 5;
    int t0 = (blockIdx.x & 31) * TB;

    // ---- per-thread constants (issue global loads early)
    int a0 = 2 * tid;
    const float4* lp = (const float4*)(Lw + (long)a0 * NF);
    float4 lf[16];
#pragma unroll
    for (int i = 0; i < 16; ++i) lf[i] = lp[i];
    float c0 = pq[b * NA + a0]     + Lb[a0];
    float c1 = pq[b * NA + a0 + 1] + Lb[a0 + 1];
    float vx = vw[a0], vy = vw[a0 + 1];

    // ---- stage cum/att slice
    if (tid < TB + 30) {
        int t = t0 - PADW + tid;
        bool ok = (t >= 0) && (t < NT);
        cum_s[tid] = ok ? cum[b * NT + t] : 0.f;
        att_s[tid] = ok ? att[b * NT + t] : 0.f;
    }

    // ---- L_w rows -> half2 registers (32 VGPRs)
    unsigned h0[16], h1[16];
#pragma unroll
    for (int i = 0; i < 8; ++i) {
        h0[2 * i]     = pkrtz(lf[i].x, lf[i].y);
        h0[2 * i + 1] = pkrtz(lf[i].z, lf[i].w);
        h1[2 * i]     = pkrtz(lf[8 + i].x, lf[8 + i].y);
        h1[2 * i + 1] = pkrtz(lf[8 + i].z, lf[8 + i].w);
    }
    __syncthreads();

    // ---- conv phase: wave w computes filters [8w, 8w+8) for all 32 tt.
    // weights are wave-uniform -> scalar loads; lanes 32-63 duplicate (cheap).
    {
        int lane = tid & 63;
        int tt = lane & 31;
        int fbu = __builtin_amdgcn_readfirstlane(tid >> 6) * 8;
        const float* cw = cwT + fbu;
        float acc[8] = {0, 0, 0, 0, 0, 0, 0, 0};
        for (int k = 0; k < KW; ++k) {
            float x0 = cum_s[tt + k];
            float x1 = att_s[tt + k];
#pragma unroll
            for (int f8 = 0; f8 < 8; ++f8) {
                acc[f8] = fmaf(x0, cw[k * NF + f8],
                          fmaf(x1, cw[(KW + k) * NF + f8], acc[f8]));
            }
        }
        if (lane < 32) {
            uint4 pk;
            pk.x = pkrtz(acc[0], acc[1]);
            pk.y = pkrtz(acc[2], acc[3]);
            pk.z = pkrtz(acc[4], acc[5]);
            pk.w = pkrtz(acc[6], acc[7]);
            *(uint4*)&cvsh[tt][fbu >> 1] = pk;   // 16B-aligned: (20*tt + fbu/2)*4
        }
    }
    __syncthreads();

    // ---- main loop: 32 tt, per-thread 2 a's, f16 dot2 against broadcast conv
    float p32[TB];
    const float* erow = enc + ((long)b * NT + t0) * NA + a0;
#pragma unroll
    for (int tt = 0; tt < TB; ++tt) {
        float2 e = *(const float2*)(erow + (long)tt * NA);
        float x0[2] = {c0 + e.x, 0.f};
        float x1[2] = {c1 + e.y, 0.f};
#pragma unroll
        for (int q = 0; q < 4; ++q) {
            uint4 cv = *(const uint4*)&cvsh[tt][4 * q];
            int p = q & 1;
            x0[p] = fdot2u(cv.x, h0[4 * q + 0], x0[p]);
            x0[p] = fdot2u(cv.y, h0[4 * q + 1], x0[p]);
            x0[p] = fdot2u(cv.z, h0[4 * q + 2], x0[p]);
            x0[p] = fdot2u(cv.w, h0[4 * q + 3], x0[p]);
            x1[p] = fdot2u(cv.x, h1[4 * q + 0], x1[p]);
            x1[p] = fdot2u(cv.y, h1[4 * q + 1], x1[p]);
            x1[p] = fdot2u(cv.z, h1[4 * q + 2], x1[p]);
            x1[p] = fdot2u(cv.w, h1[4 * q + 3], x1[p]);
        }
        p32[tt] = fast_tanh(x0[0] + x0[1]) * vx + fast_tanh(x1[0] + x1[1]) * vy;
    }

    // ---- reduction: register butterfly transpose-reduce across the wave
    // stage m: keep the half selected by (lane&m), receive partner's same half.
    {
        int lane = tid & 63;
        int wv   = tid >> 6;
        int len = TB;
#pragma unroll
        for (int m = 1; m <= 16; m <<= 1) {
            int half = len >> 1;
            bool up = (lane & m) != 0;
#pragma unroll
            for (int i = 0; i < 16; ++i) {
                if (i < half) {
                    float send = up ? p32[i] : p32[i + half];
                    float keep = up ? p32[i + half] : p32[i];
                    p32[i] = keep + __shfl_xor(send, m, 64);
                }
            }
            len = half;
        }
        float v = p32[0] + __shfl_xor(p32[0], 32, 64);
        // tt index held by this lane: bit-reversed 5-bit lane id
        int l = lane & 31;
        int tt = ((l & 1) << 4) | ((l & 2) << 2) | (l & 4) | ((l & 8) >> 2) | ((l & 16) >> 4);
        if (lane < 32) wred[wv][tt] = v;
    }
    __syncthreads();
    if (tid < 32) {
        float u = wred[0][tid] + wred[1][tid] + wred[2][tid] + wred[3][tid];
        sout[b * NT + t0 + tid] = fast_sigmoid(u);
    }
}

// ---------------- kernel C: normalize with alpha recursion + mask (in place)
__global__ __launch_bounds__(256) void lsa_norm(
    const float* __restrict__ alpha, const int* __restrict__ plen,
    float* __restrict__ out)
{
    __shared__ float red[4];
    int tid = threadIdx.x;
    int b = blockIdx.x;
    int pl = plen[b];
    float w[4];
    float psum = 0.f;
#pragma unroll
    for (int j = 0; j < 4; ++j) {
        int t = tid + 256 * j;
        float s   = out[b * NT + t];
        float al  = alpha[b * NT + t];
        float am1 = (t >= 1) ? alpha[b * NT + t - 1] : 0.f;
        float am2 = (t >= 2) ? alpha[b * NT + t - 2] : 0.f;
        float val = (t < pl) ? (al + am1 + am2 + 1e-7f) * s : 0.f;
        w[j] = val;
        psum += val;
    }
#pragma unroll
    for (int m = 32; m >= 1; m >>= 1) psum += __shfl_xor(psum, m, 64);
    int lane = tid & 63, wid = tid >> 6;
    if (lane == 0) red[wid] = psum;
    __syncthreads();
    float total = red[0] + red[1] + red[2] + red[3];
    float inv = 1.0f / total;
#pragma unroll
    for (int j = 0; j < 4; ++j) {
        int t = tid + 256 * j;
        out[b * NT + t] = w[j] * inv;
    }
}

extern "C" void kernel_launch(void* const* d_in, const int* in_sizes, int n_in,
                              void* d_out, int out_size, void* d_ws, size_t ws_size,
                              hipStream_t stream)
{
    const float* enc   = (const float*)d_in[0];
    const float* query = (const float*)d_in[1];
    const float* cum   = (const float*)d_in[2];
    const float* att   = (const float*)d_in[3];
    const float* alpha = (const float*)d_in[4];
    const float* convw = (const float*)d_in[5];
    const float* Lw    = (const float*)d_in[6];
    const float* Lb    = (const float*)d_in[7];
    const float* Ww    = (const float*)d_in[8];
    const float* Wb    = (const float*)d_in[9];
    const float* vw    = (const float*)d_in[10];
    const int*   plen  = (const int*)d_in[12];

    float* pq  = (float*)d_ws;                       // 64*512 floats = 128 KB
    float* cwT = (float*)d_ws + NB * NA;             // 1984 floats
    float* sout = (float*)d_out;

    lsa_pq  <<<NB * 2,         256, 0, stream>>>(query, Ww, Wb, convw, pq, cwT);
    lsa_main<<<NB * (NT / TB), 256, 0, stream>>>(enc, cum, att, cwT, Lw, Lb, vw, pq, sout);
    lsa_norm<<<NB,             256, 0, stream>>>(alpha, plen, sout);
}